// Round 1
// baseline (621.741 us; speedup 1.0000x reference)
//
#include <hip/hip_runtime.h>
#include <cmath>
#include <cstdint>
#include <cstddef>

#define NT 17
#define NP 45
// B=64, S=512, H=768

// ---------------------------------------------------------------------------
// Kernel 1: logits = hidden @ [W_tag | W_pos] + bias   (f32 vector GEMM)
// 512 blocks x 256 thr; block tile 64 rows x 62 cols; K chunks of 32 in LDS.
// ---------------------------------------------------------------------------
__global__ __launch_bounds__(256) void gemm_logits(
    const float* __restrict__ hidden, const float* __restrict__ Wt,
    const float* __restrict__ bt, const float* __restrict__ Wp,
    const float* __restrict__ bp, float* __restrict__ tagL,
    float* __restrict__ posL)
{
    __shared__ float As[32 * 68];   // [k][r], stride 68 (pad: bank spread + 16B align)
    __shared__ float Bs[32 * 64];   // [k][c]
    const int tid = threadIdx.x;
    const int rg = tid >> 4;        // 0..15  (row group of 4)
    const int cg = tid & 15;        // 0..15  (col group of 4)
    const int row0 = blockIdx.x * 64;

    float acc[4][4];
#pragma unroll
    for (int a = 0; a < 4; ++a)
#pragma unroll
        for (int b = 0; b < 4; ++b) acc[a][b] = 0.f;

    for (int kc = 0; kc < 768; kc += 32) {
        __syncthreads();
        // stage A transposed: As[k][r] = hidden[row0+r][kc+k]
#pragma unroll
        for (int it = 0; it < 2; ++it) {
            int idx = tid + it * 256;
            int r = idx >> 3, q = idx & 7;
            float4 h = *(const float4*)(hidden + (size_t)(row0 + r) * 768 + kc + q * 4);
            As[(q * 4 + 0) * 68 + r] = h.x;
            As[(q * 4 + 1) * 68 + r] = h.y;
            As[(q * 4 + 2) * 68 + r] = h.z;
            As[(q * 4 + 3) * 68 + r] = h.w;
        }
        // stage B: Bs[k][c] = W[kc+k][c] (tag cols 0..16, pos cols 17..61, pad 0)
#pragma unroll
        for (int it = 0; it < 8; ++it) {
            int idx = tid + it * 256;
            int k = idx >> 6, c = idx & 63;
            float v = 0.f;
            if (c < NT) v = Wt[(kc + k) * NT + c];
            else if (c < NT + NP) v = Wp[(kc + k) * NP + (c - NT)];
            Bs[idx] = v;
        }
        __syncthreads();
#pragma unroll
        for (int kk = 0; kk < 32; ++kk) {
            float4 a4 = *(const float4*)(As + kk * 68 + rg * 4);
            float4 b4 = *(const float4*)(Bs + kk * 64 + cg * 4);
            float av[4] = {a4.x, a4.y, a4.z, a4.w};
            float bv[4] = {b4.x, b4.y, b4.z, b4.w};
#pragma unroll
            for (int jr = 0; jr < 4; ++jr)
#pragma unroll
                for (int jc = 0; jc < 4; ++jc)
                    acc[jr][jc] = fmaf(av[jr], bv[jc], acc[jr][jc]);
        }
    }
#pragma unroll
    for (int jr = 0; jr < 4; ++jr) {
        size_t r = (size_t)row0 + rg * 4 + jr;
#pragma unroll
        for (int jc = 0; jc < 4; ++jc) {
            int c = cg * 4 + jc;
            if (c < NT) tagL[r * NT + c] = acc[jr][jc] + bt[c];
            else if (c < NT + NP) posL[r * NP + (c - NT)] = acc[jr][jc] + bp[c - NT];
        }
    }
}

// ---------------------------------------------------------------------------
// Kernel 2: per-row logsumexp for log_softmax (tag over 17, pos over 45)
// ---------------------------------------------------------------------------
__global__ __launch_bounds__(256) void lse_kernel(
    const float* __restrict__ tagL, const float* __restrict__ posL,
    float* __restrict__ lseT, float* __restrict__ lseP)
{
    int row = blockIdx.x * 256 + threadIdx.x;   // 32768 rows total
    {
        const float* p = tagL + (size_t)row * NT;
        float m = p[0];
#pragma unroll
        for (int i = 1; i < NT; ++i) m = fmaxf(m, p[i]);
        float s = 0.f;
#pragma unroll
        for (int i = 0; i < NT; ++i) s += __expf(p[i] - m);
        lseT[row] = m + __logf(s);
    }
    {
        const float* p = posL + (size_t)row * NP;
        float m = p[0];
#pragma unroll
        for (int i = 1; i < NP; ++i) m = fmaxf(m, p[i]);
        float s = 0.f;
#pragma unroll
        for (int i = 0; i < NP; ++i) s += __expf(p[i] - m);
        lseP[row] = m + __logf(s);
    }
}

// ---------------------------------------------------------------------------
// Kernel 3: the four CRF scans, one wave per (b, role). 256 blocks x 64 thr.
// ---------------------------------------------------------------------------
struct __align__(16) SmemScan {
    float e[2][64 * NP];            // emission chunk double buffer (23040 B)
    float pbuf[48];                 // score / p broadcast vector
    int   msk[2][64];               // mask chunk
    unsigned char hist[511 * NP];   // viterbi backpointers (22995 B)
    unsigned char pred[512];        // decoded path
};

template <int T>
__device__ inline void preload_chunk(SmemScan* sm, int buf, int b, int t0,
    const float* __restrict__ logits, const float* __restrict__ lse,
    const int* __restrict__ mask, bool sub)
{
    const int lane = threadIdx.x;
    const float* src = logits + ((size_t)b * 512 + t0) * T;
    for (int i = lane; i < 64 * T; i += 64) {
        float v = src[i];
        if (sub) v -= lse[(size_t)b * 512 + t0 + i / T];
        sm->e[buf][i] = v;
    }
    sm->msk[buf][lane] = mask[b * 512 + t0 + lane];
}

// NLL forward scan + denominator + numerator (target path score)
template <int T, int PT>
__device__ void nll_scan(SmemScan* sm, int b,
    const float* __restrict__ logits, const float* __restrict__ lse,
    const int* __restrict__ mask, const int* __restrict__ targ,
    const float* __restrict__ start, const float* __restrict__ trans,
    const float* __restrict__ endv, float* __restrict__ den, float* __restrict__ num)
{
    const int lane = threadIdx.x;
    const int jj = (lane < T) ? lane : (T - 1);
    float Ecol[T];
#pragma unroll
    for (int i = 0; i < T; ++i) Ecol[i] = __expf(trans[i * T + jj]);

    preload_chunk<T>(sm, 0, b, 0, logits, lse, mask, true);
    __syncthreads();
    float sc = start[jj] + sm->e[0][jj];

    int cb = 0;
    for (int c = 0; c < 8; ++c) {
        if (c < 7) preload_chunk<T>(sm, cb ^ 1, b, (c + 1) * 64, logits, lse, mask, true);
        const float* eb = sm->e[cb];
        const int* mb = sm->msk[cb];
        for (int s = (c == 0) ? 1 : 0; s < 64; ++s) {
            float c0 = __shfl(sc, 0);
            float p = __expf(sc - c0);
            if (lane < PT) sm->pbuf[lane] = (lane < T) ? p : 0.f;
            __syncthreads();
            float pv[PT];
#pragma unroll
            for (int q = 0; q < PT / 4; ++q) {
                float4 v4 = *(const float4*)(sm->pbuf + q * 4);
                pv[q * 4 + 0] = v4.x; pv[q * 4 + 1] = v4.y;
                pv[q * 4 + 2] = v4.z; pv[q * 4 + 3] = v4.w;
            }
            float d0 = 0.f, d1 = 0.f, d2 = 0.f, d3 = 0.f;
#pragma unroll
            for (int i = 0; i < T; ++i) {
                if ((i & 3) == 0) d0 = fmaf(pv[i], Ecol[i], d0);
                else if ((i & 3) == 1) d1 = fmaf(pv[i], Ecol[i], d1);
                else if ((i & 3) == 2) d2 = fmaf(pv[i], Ecol[i], d2);
                else d3 = fmaf(pv[i], Ecol[i], d3);
            }
            float dot = (d0 + d1) + (d2 + d3);
            float nxt = __logf(dot) + c0 + eb[s * T + jj];
            bool keep = mb[s] > 0;
            sc = keep ? nxt : sc;
        }
        __syncthreads();
        cb ^= 1;
    }
    // denominator = logsumexp_j(score + end)
    float v = (lane < T) ? (sc + endv[lane]) : -INFINITY;
    float m = v;
#pragma unroll
    for (int o = 32; o; o >>= 1) m = fmaxf(m, __shfl_xor(m, o));
    float se = (lane < T) ? __expf(v - m) : 0.f;
#pragma unroll
    for (int o = 32; o; o >>= 1) se += __shfl_xor(se, o);
    if (lane == 0) den[b] = m + __logf(se);

    // numerator: score of target path (parallel over t, contiguous-prefix mask)
    float part = 0.f; int Lc = 0;
    for (int t = lane; t < 512; t += 64) {
        int mt = mask[b * 512 + t];
        Lc += (mt > 0);
        if (t >= 1 && mt > 0) {
            int tg = targ[b * 512 + t];
            int pg = targ[b * 512 + t - 1];
            part += trans[pg * T + tg]
                  + logits[((size_t)b * 512 + t) * T + tg] - lse[b * 512 + t];
        }
    }
#pragma unroll
    for (int o = 32; o; o >>= 1) { part += __shfl_xor(part, o); Lc += __shfl_xor(Lc, o); }
    if (lane == 0) {
        int t0g = targ[b * 512];
        num[b] = start[t0g] + logits[(size_t)b * 512 * T + t0g] - lse[b * 512]
               + part + endv[targ[b * 512 + Lc - 1]];
    }
}

// Viterbi forward + backtrace; writes predictions (as f32) to outp[b*512..]
template <int T, int PT>
__device__ void vit_scan(SmemScan* sm, int b,
    const float* __restrict__ logits, const int* __restrict__ mask,
    const float* __restrict__ start, const float* __restrict__ trans,
    const float* __restrict__ endv, float* __restrict__ outp)
{
    const int lane = threadIdx.x;
    const int jj = (lane < T) ? lane : (T - 1);
    float Tcol[T];
#pragma unroll
    for (int i = 0; i < T; ++i) Tcol[i] = trans[i * T + jj];

    preload_chunk<T>(sm, 0, b, 0, logits, (const float*)nullptr, mask, false);
    __syncthreads();
    float sc = start[jj] + sm->e[0][jj];

    int cb = 0;
    for (int c = 0; c < 8; ++c) {
        if (c < 7) preload_chunk<T>(sm, cb ^ 1, b, (c + 1) * 64, logits, nullptr, mask, false);
        const float* eb = sm->e[cb];
        const int* mb = sm->msk[cb];
        for (int s = (c == 0) ? 1 : 0; s < 64; ++s) {
            int t = c * 64 + s;
            if (lane < PT) sm->pbuf[lane] = sc;
            __syncthreads();
            float pv[PT];
#pragma unroll
            for (int q = 0; q < PT / 4; ++q) {
                float4 v4 = *(const float4*)(sm->pbuf + q * 4);
                pv[q * 4 + 0] = v4.x; pv[q * 4 + 1] = v4.y;
                pv[q * 4 + 2] = v4.z; pv[q * 4 + 3] = v4.w;
            }
            float m = -INFINITY; int am = 0;
#pragma unroll
            for (int i = 0; i < T; ++i) {
                float svv = pv[i] + Tcol[i];
                bool g = svv > m;          // strict > keeps FIRST max (jnp.argmax)
                m = g ? svv : m;
                am = g ? i : am;
            }
            bool keep = mb[s] > 0;
            if (lane < T)
                sm->hist[(t - 1) * T + lane] = (unsigned char)(keep ? am : lane);
            float nxt = m + eb[s * T + jj];
            sc = keep ? nxt : sc;
        }
        __syncthreads();
        cb ^= 1;
    }
    float v = (lane < T) ? (sc + endv[lane]) : -INFINITY;
    float m = v;
#pragma unroll
    for (int o = 32; o; o >>= 1) m = fmaxf(m, __shfl_xor(m, o));
    unsigned long long bal = __ballot(v == m);
    int last = __ffsll(bal) - 1;           // first (lowest) index among maxima
    __syncthreads();
    if (lane == 0) {
        int cur = last;
        sm->pred[511] = (unsigned char)cur;
        for (int t = 511; t >= 1; --t) {
            cur = sm->hist[(t - 1) * T + cur];
            sm->pred[t - 1] = (unsigned char)cur;
        }
    }
    __syncthreads();
    for (int k = lane; k < 512; k += 64)
        outp[(size_t)b * 512 + k] = (float)sm->pred[k];
}

__global__ __launch_bounds__(64) void scan_kernel(
    const float* tagL, const float* posL, const float* lseT, const float* lseP,
    const int* mask, const int* tgT, const int* tgP,
    const float* startT, const float* transT, const float* endT,
    const float* startP, const float* transP, const float* endP,
    float* denT, float* denP, float* numT, float* numP, float* out)
{
    __shared__ SmemScan sm;
    int bid = blockIdx.x;
    if (bid < 64)
        vit_scan<NP, 48>(&sm, bid, posL, mask, startP, transP, endP, out + 32768);
    else if (bid < 128)
        nll_scan<NP, 48>(&sm, bid - 64, posL, lseP, mask, tgP, startP, transP, endP, denP, numP);
    else if (bid < 192)
        vit_scan<NT, 20>(&sm, bid - 128, tagL, mask, startT, transT, endT, out);
    else
        nll_scan<NT, 20>(&sm, bid - 192, tagL, lseT, mask, tgT, startT, transT, endT, denT, numT);
}

// ---------------------------------------------------------------------------
// Kernel 4: losses = -mean(num - den)
// ---------------------------------------------------------------------------
__global__ __launch_bounds__(64) void finalize_kernel(
    const float* numT, const float* denT, const float* numP, const float* denP,
    float* out)
{
    int lane = threadIdx.x;
    float dT = numT[lane] - denT[lane];
    float dP = numP[lane] - denP[lane];
#pragma unroll
    for (int o = 32; o; o >>= 1) { dT += __shfl_xor(dT, o); dP += __shfl_xor(dP, o); }
    if (lane == 0) {
        out[65536] = -dT / 64.f;
        out[65537] = -dP / 64.f;
    }
}

// ---------------------------------------------------------------------------
extern "C" void kernel_launch(void* const* d_in, const int* in_sizes, int n_in,
                              void* d_out, int out_size, void* d_ws, size_t ws_size,
                              hipStream_t stream)
{
    const float* hidden = (const float*)d_in[0];
    const int*   mask   = (const int*)d_in[1];
    const int*   tgT    = (const int*)d_in[2];
    const int*   tgP    = (const int*)d_in[3];
    const float* Wt     = (const float*)d_in[4];
    const float* bt     = (const float*)d_in[5];
    const float* Wp     = (const float*)d_in[6];
    const float* bp     = (const float*)d_in[7];
    const float* startT = (const float*)d_in[8];
    const float* transT = (const float*)d_in[9];
    const float* endT   = (const float*)d_in[10];
    const float* startP = (const float*)d_in[11];
    const float* transP = (const float*)d_in[12];
    const float* endP   = (const float*)d_in[13];

    float* ws   = (float*)d_ws;
    float* tagL = ws;                       // 64*512*17 = 557056
    float* posL = tagL + 557056;            // 64*512*45 = 1474560
    float* lseT = posL + 1474560;           // 32768
    float* lseP = lseT + 32768;             // 32768
    float* denT = lseP + 32768;             // 64
    float* denP = denT + 64;                // 64
    float* numT = denP + 64;                // 64
    float* numP = numT + 64;                // 64
    float* out  = (float*)d_out;

    gemm_logits<<<512, 256, 0, stream>>>(hidden, Wt, bt, Wp, bp, tagL, posL);
    lse_kernel<<<128, 256, 0, stream>>>(tagL, posL, lseT, lseP);
    scan_kernel<<<256, 64, 0, stream>>>(tagL, posL, lseT, lseP, mask, tgT, tgP,
        startT, transT, endT, startP, transP, endP, denT, denP, numT, numP, out);
    finalize_kernel<<<1, 64, 0, stream>>>(numT, denT, numP, denP, out);
}

// Round 2
// 538.494 us; speedup vs baseline: 1.1546x; 1.1546x over previous
//
#include <hip/hip_runtime.h>
#include <cmath>
#include <cstdint>
#include <cstddef>

#define NT 17
#define NP 45
#define CH 8
// B=64, S=512, H=768

__device__ __forceinline__ float rlane(float v, int k) {
    return __int_as_float(__builtin_amdgcn_readlane(__float_as_int(v), k));
}
__device__ __forceinline__ float rfirst(float v) {
    return __int_as_float(__builtin_amdgcn_readfirstlane(__float_as_int(v)));
}

// ---------------------------------------------------------------------------
// Kernel 1: logits = hidden @ [W_tag | W_pos] + bias   (f32 vector GEMM)
// ---------------------------------------------------------------------------
__global__ __launch_bounds__(256) void gemm_logits(
    const float* __restrict__ hidden, const float* __restrict__ Wt,
    const float* __restrict__ bt, const float* __restrict__ Wp,
    const float* __restrict__ bp, float* __restrict__ tagL,
    float* __restrict__ posL)
{
    __shared__ float As[32 * 68];
    __shared__ float Bs[32 * 64];
    const int tid = threadIdx.x;
    const int rg = tid >> 4;
    const int cg = tid & 15;
    const int row0 = blockIdx.x * 64;

    float acc[4][4];
#pragma unroll
    for (int a = 0; a < 4; ++a)
#pragma unroll
        for (int b = 0; b < 4; ++b) acc[a][b] = 0.f;

    for (int kc = 0; kc < 768; kc += 32) {
        __syncthreads();
#pragma unroll
        for (int it = 0; it < 2; ++it) {
            int idx = tid + it * 256;
            int r = idx >> 3, q = idx & 7;
            float4 h = *(const float4*)(hidden + (size_t)(row0 + r) * 768 + kc + q * 4);
            As[(q * 4 + 0) * 68 + r] = h.x;
            As[(q * 4 + 1) * 68 + r] = h.y;
            As[(q * 4 + 2) * 68 + r] = h.z;
            As[(q * 4 + 3) * 68 + r] = h.w;
        }
#pragma unroll
        for (int it = 0; it < 8; ++it) {
            int idx = tid + it * 256;
            int k = idx >> 6, c = idx & 63;
            float v = 0.f;
            if (c < NT) v = Wt[(kc + k) * NT + c];
            else if (c < NT + NP) v = Wp[(kc + k) * NP + (c - NT)];
            Bs[idx] = v;
        }
        __syncthreads();
#pragma unroll
        for (int kk = 0; kk < 32; ++kk) {
            float4 a4 = *(const float4*)(As + kk * 68 + rg * 4);
            float4 b4 = *(const float4*)(Bs + kk * 64 + cg * 4);
            float av[4] = {a4.x, a4.y, a4.z, a4.w};
            float bv[4] = {b4.x, b4.y, b4.z, b4.w};
#pragma unroll
            for (int jr = 0; jr < 4; ++jr)
#pragma unroll
                for (int jc = 0; jc < 4; ++jc)
                    acc[jr][jc] = fmaf(av[jr], bv[jc], acc[jr][jc]);
        }
    }
#pragma unroll
    for (int jr = 0; jr < 4; ++jr) {
        size_t r = (size_t)row0 + rg * 4 + jr;
#pragma unroll
        for (int jc = 0; jc < 4; ++jc) {
            int c = cg * 4 + jc;
            if (c < NT) tagL[r * NT + c] = acc[jr][jc] + bt[c];
            else if (c < NT + NP) posL[r * NP + (c - NT)] = acc[jr][jc] + bp[c - NT];
        }
    }
}

// ---------------------------------------------------------------------------
// Kernel 2: the four CRF scans. One wave per (b, role); 256 blocks x 64 thr.
// log_softmax dropped: num-den is invariant to per-step uniform shifts.
// ---------------------------------------------------------------------------
template <int T>
__device__ void nll_scan(int b,
    const float* __restrict__ logits, const int* __restrict__ mask,
    const int* __restrict__ targ, const float* __restrict__ start,
    const float* __restrict__ trans, const float* __restrict__ endv,
    float* __restrict__ den, float* __restrict__ num)
{
    const int lane = threadIdx.x;
    const int jj = (lane < T) ? lane : (T - 1);
    float Ecol[T];
#pragma unroll
    for (int i = 0; i < T; ++i) Ecol[i] = __expf(trans[i * T + jj]);
    const float sjj = start[jj];
    const float* eptr = logits + (size_t)b * 512 * T + jj;
    const int* mptr = mask + b * 512;

    float eb[CH], en[CH];
    int mb, mn = 0;
#pragma unroll
    for (int k = 0; k < CH; ++k) { eb[k] = eptr[k * T]; en[k] = 0.f; }
    mb = mptr[lane & (CH - 1)];

    float sc = 0.f;
    for (int c = 0; c < 64; ++c) {
        if (c < 63) {
            const float* ep2 = eptr + (c + 1) * CH * T;
#pragma unroll
            for (int k = 0; k < CH; ++k) en[k] = ep2[k * T];
            mn = mptr[(c + 1) * CH + (lane & (CH - 1))];
        }
#pragma unroll
        for (int s = 0; s < CH; ++s) {
            float c0 = rfirst(sc);
            float p = __expf(sc - c0);
            float d0 = 0.f, d1 = 0.f, d2 = 0.f, d3 = 0.f;
#pragma unroll
            for (int i = 0; i < T; ++i) {
                float pk = rlane(p, i);
                if ((i & 3) == 0) d0 = fmaf(pk, Ecol[i], d0);
                else if ((i & 3) == 1) d1 = fmaf(pk, Ecol[i], d1);
                else if ((i & 3) == 2) d2 = fmaf(pk, Ecol[i], d2);
                else d3 = fmaf(pk, Ecol[i], d3);
            }
            float nxt = __logf((d0 + d1) + (d2 + d3)) + c0 + eb[s];
            int mk = __builtin_amdgcn_readlane(mb, s);
            bool first = (c == 0) && (s == 0);
            sc = first ? (sjj + eb[0]) : ((mk > 0) ? nxt : sc);
        }
#pragma unroll
        for (int k = 0; k < CH; ++k) eb[k] = en[k];
        mb = mn;
    }
    // denominator
    float v = (lane < T) ? (sc + endv[lane]) : -1e30f;
    float m = v;
#pragma unroll
    for (int o = 32; o; o >>= 1) m = fmaxf(m, __shfl_xor(m, o));
    float se = (lane < T) ? __expf(v - m) : 0.f;
#pragma unroll
    for (int o = 32; o; o >>= 1) se += __shfl_xor(se, o);
    if (lane == 0) den[b] = m + __logf(se);

    // numerator (raw logits; lse cancels in num-den)
    float part = 0.f; int Lc = 0;
    for (int t = lane; t < 512; t += 64) {
        int mt = mask[b * 512 + t];
        Lc += (mt > 0);
        if (t >= 1 && mt > 0) {
            int tg = targ[b * 512 + t];
            int pg = targ[b * 512 + t - 1];
            part += trans[pg * T + tg] + logits[((size_t)b * 512 + t) * T + tg];
        }
    }
#pragma unroll
    for (int o = 32; o; o >>= 1) { part += __shfl_xor(part, o); Lc += __shfl_xor(Lc, o); }
    if (lane == 0) {
        int t0g = targ[b * 512];
        num[b] = start[t0g] + logits[(size_t)b * 512 * T + t0g]
               + part + endv[targ[b * 512 + Lc - 1]];
    }
}

// Viterbi forward, max only; stores score vectors for later argmax recompute.
template <int T>
__device__ void vit_fwd(int b,
    const float* __restrict__ logits, const int* __restrict__ mask,
    const float* __restrict__ start, const float* __restrict__ trans,
    float* __restrict__ score)
{
    const int lane = threadIdx.x;
    const int jj = (lane < T) ? lane : (T - 1);
    float Tcol[T];
#pragma unroll
    for (int i = 0; i < T; ++i) Tcol[i] = trans[i * T + jj];
    const float sjj = start[jj];
    const float* eptr = logits + (size_t)b * 512 * T + jj;
    const int* mptr = mask + b * 512;
    float* sptr = score + (size_t)b * 512 * T + lane;

    float eb[CH], en[CH];
    int mb, mn = 0;
#pragma unroll
    for (int k = 0; k < CH; ++k) { eb[k] = eptr[k * T]; en[k] = 0.f; }
    mb = mptr[lane & (CH - 1)];

    float sc = 0.f;
    for (int c = 0; c < 64; ++c) {
        if (c < 63) {
            const float* ep2 = eptr + (c + 1) * CH * T;
#pragma unroll
            for (int k = 0; k < CH; ++k) en[k] = ep2[k * T];
            mn = mptr[(c + 1) * CH + (lane & (CH - 1))];
        }
#pragma unroll
        for (int s = 0; s < CH; ++s) {
            float m = -1e30f;
#pragma unroll
            for (int i = 0; i < T; i += 2) {
                float ca = rlane(sc, i) + Tcol[i];
                if (i + 1 < T) {
                    float cb = rlane(sc, i + 1) + Tcol[i + 1];
                    m = fmaxf(fmaxf(m, ca), cb);   // -> v_max3
                } else {
                    m = fmaxf(m, ca);
                }
            }
            float nxt = m + eb[s];
            int mk = __builtin_amdgcn_readlane(mb, s);
            bool first = (c == 0) && (s == 0);
            sc = first ? (sjj + eb[0]) : ((mk > 0) ? nxt : sc);
            if (lane < T) sptr[(size_t)(c * CH + s) * T] = sc;
        }
#pragma unroll
        for (int k = 0; k < CH; ++k) eb[k] = en[k];
        mb = mn;
    }
}

__global__ __launch_bounds__(64) void scan_kernel(
    const float* tagL, const float* posL, const int* mask,
    const int* tgT, const int* tgP,
    const float* startT, const float* transT, const float* endT,
    const float* startP, const float* transP, const float* endP,
    float* scoreT, float* scoreP,
    float* denT, float* denP, float* numT, float* numP)
{
    int bid = blockIdx.x;
    if (bid < 64)
        vit_fwd<NP>(bid, posL, mask, startP, transP, scoreP);
    else if (bid < 128)
        nll_scan<NP>(bid - 64, posL, mask, tgP, startP, transP, endP, denP, numP);
    else if (bid < 192)
        vit_fwd<NT>(bid - 128, tagL, mask, startT, transT, scoreT);
    else
        nll_scan<NT>(bid - 192, tagL, mask, tgT, startT, transT, endT, denT, numT);
}

// ---------------------------------------------------------------------------
// Kernel 3: recompute Viterbi backpointers massively parallel over (b,t).
// Bit-identical adds vs forward pass => identical argmax.
// ---------------------------------------------------------------------------
template <int T>
__device__ void hist_block(int b, int tc,
    const float* __restrict__ score, const int* __restrict__ mask,
    const float* __restrict__ trans, unsigned char* __restrict__ hist)
{
    const int wave = threadIdx.x >> 6;
    const int lane = threadIdx.x & 63;
    const int jj = (lane < T) ? lane : (T - 1);
    float Tcol[T];
#pragma unroll
    for (int i = 0; i < T; ++i) Tcol[i] = trans[i * T + jj];
    for (int q = 0; q < 16; ++q) {
        int t = tc * 64 + wave * 16 + q;
        if (t < 1) continue;
        int mt = mask[b * 512 + t];
        int hv;
        if (mt > 0) {
            float sv = score[((size_t)b * 512 + t - 1) * T + jj];
            float mx = -1e30f; int am = 0;
#pragma unroll
            for (int i = 0; i < T; ++i) {
                float cand = rlane(sv, i) + Tcol[i];
                bool g = cand > mx;            // strict > keeps FIRST max
                mx = g ? cand : mx;
                am = g ? i : am;
            }
            hv = am;
        } else {
            hv = jj;                           // identity when masked
        }
        if (lane < T)
            hist[((size_t)b * 512 + (t - 1)) * T + lane] = (unsigned char)hv;
    }
}

__global__ __launch_bounds__(256) void hist_kernel(
    const float* scoreT, const float* scoreP, const int* mask,
    const float* transT, const float* transP,
    unsigned char* histT, unsigned char* histP)
{
    int blk = blockIdx.x;
    if (blk < 512) hist_block<NP>(blk >> 3, blk & 7, scoreP, mask, transP, histP);
    else { blk -= 512; hist_block<NT>(blk >> 3, blk & 7, scoreT, mask, transT, histT); }
}

// ---------------------------------------------------------------------------
// Kernel 4: backtrace with pointer-jump composition (serial chain 511 -> 63).
// ---------------------------------------------------------------------------
template <int T>
__device__ void backtrace(int b, const float* __restrict__ score,
    const unsigned char* __restrict__ hist, const float* __restrict__ endv,
    float* __restrict__ outp, unsigned char* sh)
{
    unsigned char* h  = sh;                    // 512*T
    unsigned char* g2 = sh + 512 * T;          // rows 0..509
    unsigned char* g4 = sh + 1024 * T;         // 127 rows (r = 3+4*a4)
    unsigned char* g8 = sh + 1024 * T + 128 * T; // 63 rows (r = 503-8a)
    unsigned char* pr = sh + 1024 * T + 192 * T; // 512
    const int lane = threadIdx.x;

    {   // stage hist to LDS (b-stride = 512*T bytes, 16B multiple)
        const int4* src = (const int4*)(hist + (size_t)b * 512 * T);
        int4* dst = (int4*)h;
        int n16 = (512 * T) / 16;
        for (int i = lane; i < n16; i += 64) dst[i] = src[i];
    }
    __syncthreads();
    // g2[r][i] = h[r][h[r+1][i]]  (maps cur at t=r+2 -> t=r)
    for (int idx = lane; idx < 510 * T; idx += 64) {
        int r = idx / T, i = idx - r * T;
        g2[idx] = h[r * T + h[(r + 1) * T + i]];
    }
    __syncthreads();
    // g4 rows r = 3+4*a4: g4[a4][i] = g2[r][ g2[r+2][i] ]  (t=r+4 -> r)
    for (int idx = lane; idx < 127 * T; idx += 64) {
        int a4 = idx / T, i = idx - a4 * T;
        int r = 3 + 4 * a4;
        g4[idx] = g2[r * T + g2[(r + 2) * T + i]];
    }
    __syncthreads();
    // g8 rows r = 503-8a: g8[a][i] = g4row(r)[ g4row(r+4)[i] ]  (t=r+8 -> r)
    for (int idx = lane; idx < 63 * T; idx += 64) {
        int a = idx / T, i = idx - a * T;
        int r = 503 - 8 * a;
        int a4lo = (r - 3) >> 2, a4hi = (r + 1) >> 2;
        g8[idx] = g4[a4lo * T + g4[a4hi * T + i]];
    }
    // last = first-index argmax(score[511] + end)
    float v = (lane < T) ? (score[((size_t)b * 512 + 511) * T + lane] + endv[lane]) : -1e30f;
    float mx = v;
#pragma unroll
    for (int o = 32; o; o >>= 1) mx = fmaxf(mx, __shfl_xor(mx, o));
    unsigned long long bal = __ballot(v == mx);
    int cur = __ffsll(bal) - 1;
    __syncthreads();
    // phase A: serial anchor chain, 63 dependent LDS reads
    int myCur = 0;
    for (int a = 0; a < 64; ++a) {
        if (lane == a) myCur = cur;
        if (a < 63) cur = g8[a * T + cur];
    }
    // phase B: each lane fills its 8-step segment
    {
        int ta = 511 - 8 * lane;
        int j = myCur;
        pr[ta] = (unsigned char)j;
        int rlo = (lane == 63) ? 0 : (ta - 7);
        for (int r = ta - 1; r >= rlo; --r) {
            j = h[r * T + j];
            pr[r] = (unsigned char)j;
        }
    }
    __syncthreads();
    for (int k = lane; k < 512; k += 64)
        outp[(size_t)b * 512 + k] = (float)pr[k];
}

__global__ __launch_bounds__(64) void backtrace_kernel(
    const float* scoreT, const float* scoreP,
    const unsigned char* histT, const unsigned char* histP,
    const float* endT, const float* endP, float* out)
{
    __shared__ __align__(16) unsigned char sh[1216 * NP + 576];
    int blk = blockIdx.x;
    if (blk < 64) backtrace<NP>(blk, scoreP, histP, endP, out + 32768, sh);
    else backtrace<NT>(blk - 64, scoreT, histT, endT, out, sh);
}

// ---------------------------------------------------------------------------
// Kernel 5: losses = -mean(num - den)
// ---------------------------------------------------------------------------
__global__ __launch_bounds__(64) void finalize_kernel(
    const float* numT, const float* denT, const float* numP, const float* denP,
    float* out)
{
    int lane = threadIdx.x;
    float dT = numT[lane] - denT[lane];
    float dP = numP[lane] - denP[lane];
#pragma unroll
    for (int o = 32; o; o >>= 1) { dT += __shfl_xor(dT, o); dP += __shfl_xor(dP, o); }
    if (lane == 0) {
        out[65536] = -dT / 64.f;
        out[65537] = -dP / 64.f;
    }
}

// ---------------------------------------------------------------------------
extern "C" void kernel_launch(void* const* d_in, const int* in_sizes, int n_in,
                              void* d_out, int out_size, void* d_ws, size_t ws_size,
                              hipStream_t stream)
{
    const float* hidden = (const float*)d_in[0];
    const int*   mask   = (const int*)d_in[1];
    const int*   tgT    = (const int*)d_in[2];
    const int*   tgP    = (const int*)d_in[3];
    const float* Wt     = (const float*)d_in[4];
    const float* bt     = (const float*)d_in[5];
    const float* Wp     = (const float*)d_in[6];
    const float* bp     = (const float*)d_in[7];
    const float* startT = (const float*)d_in[8];
    const float* transT = (const float*)d_in[9];
    const float* endT   = (const float*)d_in[10];
    const float* startP = (const float*)d_in[11];
    const float* transP = (const float*)d_in[12];
    const float* endP   = (const float*)d_in[13];

    float* ws     = (float*)d_ws;
    float* tagL   = ws;                         // 557056
    float* posL   = tagL + 557056;              // 1474560
    float* scoreT = posL + 1474560;             // 557056
    float* scoreP = scoreT + 557056;            // 1474560
    float* denT   = scoreP + 1474560;           // 64
    float* denP   = denT + 64;
    float* numT   = denP + 64;
    float* numP   = numT + 64;
    unsigned char* histT = (unsigned char*)(numP + 64);       // 64*512*17 B
    unsigned char* histP = histT + (size_t)64 * 512 * NT;     // 64*512*45 B
    float* out = (float*)d_out;

    gemm_logits<<<512, 256, 0, stream>>>(hidden, Wt, bt, Wp, bp, tagL, posL);
    scan_kernel<<<256, 64, 0, stream>>>(tagL, posL, mask, tgT, tgP,
        startT, transT, endT, startP, transP, endP,
        scoreT, scoreP, denT, denP, numT, numP);
    hist_kernel<<<1024, 256, 0, stream>>>(scoreT, scoreP, mask, transT, transP,
        histT, histP);
    backtrace_kernel<<<128, 64, 0, stream>>>(scoreT, scoreP, histT, histP,
        endT, endP, out);
    finalize_kernel<<<1, 64, 0, stream>>>(numT, denT, numP, denP, out);
}

// Round 3
// 528.179 us; speedup vs baseline: 1.1771x; 1.0195x over previous
//
#include <hip/hip_runtime.h>
#include <cmath>
#include <cstdint>
#include <cstddef>

#define NT 17
#define NP 45
#define CH 8
// B=64, S=512, H=768

__device__ __forceinline__ float rfirst(float v) {
    return __int_as_float(__builtin_amdgcn_readfirstlane(__float_as_int(v)));
}
__device__ __forceinline__ float rlane(float v, int k) {
    return __int_as_float(__builtin_amdgcn_readlane(__float_as_int(v), k));
}

// ---------------------------------------------------------------------------
// Kernel 1: logits = hidden @ [W_tag | W_pos] + bias   (f32 vector GEMM)
// ---------------------------------------------------------------------------
__global__ __launch_bounds__(256) void gemm_logits(
    const float* __restrict__ hidden, const float* __restrict__ Wt,
    const float* __restrict__ bt, const float* __restrict__ Wp,
    const float* __restrict__ bp, float* __restrict__ tagL,
    float* __restrict__ posL)
{
    __shared__ float As[32 * 68];
    __shared__ float Bs[32 * 64];
    const int tid = threadIdx.x;
    const int rg = tid >> 4;
    const int cg = tid & 15;
    const int row0 = blockIdx.x * 64;

    float acc[4][4];
#pragma unroll
    for (int a = 0; a < 4; ++a)
#pragma unroll
        for (int b = 0; b < 4; ++b) acc[a][b] = 0.f;

    for (int kc = 0; kc < 768; kc += 32) {
        __syncthreads();
#pragma unroll
        for (int it = 0; it < 2; ++it) {
            int idx = tid + it * 256;
            int r = idx >> 3, q = idx & 7;
            float4 h = *(const float4*)(hidden + (size_t)(row0 + r) * 768 + kc + q * 4);
            As[(q * 4 + 0) * 68 + r] = h.x;
            As[(q * 4 + 1) * 68 + r] = h.y;
            As[(q * 4 + 2) * 68 + r] = h.z;
            As[(q * 4 + 3) * 68 + r] = h.w;
        }
#pragma unroll
        for (int it = 0; it < 8; ++it) {
            int idx = tid + it * 256;
            int k = idx >> 6, c = idx & 63;
            float v = 0.f;
            if (c < NT) v = Wt[(kc + k) * NT + c];
            else if (c < NT + NP) v = Wp[(kc + k) * NP + (c - NT)];
            Bs[idx] = v;
        }
        __syncthreads();
#pragma unroll
        for (int kk = 0; kk < 32; ++kk) {
            float4 a4 = *(const float4*)(As + kk * 68 + rg * 4);
            float4 b4 = *(const float4*)(Bs + kk * 64 + cg * 4);
            float av[4] = {a4.x, a4.y, a4.z, a4.w};
            float bv[4] = {b4.x, b4.y, b4.z, b4.w};
#pragma unroll
            for (int jr = 0; jr < 4; ++jr)
#pragma unroll
                for (int jc = 0; jc < 4; ++jc)
                    acc[jr][jc] = fmaf(av[jr], bv[jc], acc[jr][jc]);
        }
    }
#pragma unroll
    for (int jr = 0; jr < 4; ++jr) {
        size_t r = (size_t)row0 + rg * 4 + jr;
#pragma unroll
        for (int jc = 0; jc < 4; ++jc) {
            int c = cg * 4 + jc;
            if (c < NT) tagL[r * NT + c] = acc[jr][jc] + bt[c];
            else if (c < NT + NP) posL[r * NP + (c - NT)] = acc[jr][jc] + bp[c - NT];
        }
    }
}

// ---------------------------------------------------------------------------
// Kernel 2: the four CRF scans. One wave per (b, role); 256 blocks x 64 thr.
// Broadcast via single-wave LDS roundtrip (no barrier needed, asm waitcnt).
// log_softmax dropped: num-den is invariant to per-step uniform shifts.
// ---------------------------------------------------------------------------
template <int T, int PAD>
__device__ void nll_scan(int b,
    const float* __restrict__ logits, const int* __restrict__ mask,
    const int* __restrict__ targ, const float* __restrict__ start,
    const float* __restrict__ trans, const float* __restrict__ endv,
    float* __restrict__ den, float* __restrict__ num, float* pbuf)
{
    const int lane = threadIdx.x;
    const int jj = (lane < T) ? lane : (T - 1);
    float Ecol[PAD];
#pragma unroll
    for (int i = 0; i < PAD; ++i) Ecol[i] = (i < T) ? __expf(trans[i * T + jj]) : 0.f;
    const float sjj = start[jj];
    const float* eptr = logits + (size_t)b * 512 * T + jj;
    const int* mptr = mask + b * 512;
    const float4* pb4 = (const float4*)pbuf;

    float eb[CH], en[CH];
    int mb, mn = 0;
#pragma unroll
    for (int k = 0; k < CH; ++k) { eb[k] = eptr[k * T]; en[k] = 0.f; }
    mb = mptr[lane & (CH - 1)];

    float sc = 0.f;
    for (int c = 0; c < 64; ++c) {
        unsigned long long kb = __ballot(mb > 0);
        if (c < 63) {
            const float* ep2 = eptr + (c + 1) * CH * T;
#pragma unroll
            for (int k = 0; k < CH; ++k) en[k] = ep2[k * T];
            mn = mptr[(c + 1) * CH + (lane & (CH - 1))];
        }
#pragma unroll
        for (int s = 0; s < CH; ++s) {
            float c0 = rfirst(sc);
            float p = __expf(sc - c0);
            pbuf[lane] = (lane < T) ? p : 0.f;
            __asm__ volatile("s_waitcnt lgkmcnt(0)" ::: "memory");
            float d0 = 0.f, d1 = 0.f, d2 = 0.f, d3 = 0.f;
#pragma unroll
            for (int q = 0; q < PAD / 4; ++q) {
                float4 v4 = pb4[q];
                d0 = fmaf(v4.x, Ecol[q * 4 + 0], d0);
                d1 = fmaf(v4.y, Ecol[q * 4 + 1], d1);
                d2 = fmaf(v4.z, Ecol[q * 4 + 2], d2);
                d3 = fmaf(v4.w, Ecol[q * 4 + 3], d3);
            }
            float nxt = __logf((d0 + d1) + (d2 + d3)) + c0 + eb[s];
            bool keep = (kb >> s) & 1ULL;
            bool first = (c == 0) && (s == 0);
            sc = first ? (sjj + eb[0]) : (keep ? nxt : sc);
        }
#pragma unroll
        for (int k = 0; k < CH; ++k) eb[k] = en[k];
        mb = mn;
    }
    // denominator
    float v = (lane < T) ? (sc + endv[lane]) : -1e30f;
    float m = v;
#pragma unroll
    for (int o = 32; o; o >>= 1) m = fmaxf(m, __shfl_xor(m, o));
    float se = (lane < T) ? __expf(v - m) : 0.f;
#pragma unroll
    for (int o = 32; o; o >>= 1) se += __shfl_xor(se, o);
    if (lane == 0) den[b] = m + __logf(se);

    // numerator (raw logits; lse cancels in num-den)
    float part = 0.f; int Lc = 0;
    for (int t = lane; t < 512; t += 64) {
        int mt = mask[b * 512 + t];
        Lc += (mt > 0);
        if (t >= 1 && mt > 0) {
            int tg = targ[b * 512 + t];
            int pg = targ[b * 512 + t - 1];
            part += trans[pg * T + tg] + logits[((size_t)b * 512 + t) * T + tg];
        }
    }
#pragma unroll
    for (int o = 32; o; o >>= 1) { part += __shfl_xor(part, o); Lc += __shfl_xor(Lc, o); }
    if (lane == 0) {
        int t0g = targ[b * 512];
        num[b] = start[t0g] + logits[(size_t)b * 512 * T + t0g]
               + part + endv[targ[b * 512 + Lc - 1]];
    }
}

// Viterbi forward, max only; stores score vectors for later argmax recompute.
template <int T, int PAD>
__device__ void vit_fwd(int b,
    const float* __restrict__ logits, const int* __restrict__ mask,
    const float* __restrict__ start, const float* __restrict__ trans,
    float* __restrict__ score, float* pbuf)
{
    const int lane = threadIdx.x;
    const int jj = (lane < T) ? lane : (T - 1);
    float Tcol[PAD];
#pragma unroll
    for (int i = 0; i < PAD; ++i) Tcol[i] = (i < T) ? trans[i * T + jj] : -1e30f;
    const float sjj = start[jj];
    const float* eptr = logits + (size_t)b * 512 * T + jj;
    const int* mptr = mask + b * 512;
    float* sptr = score + (size_t)b * 512 * T + lane;
    const float4* pb4 = (const float4*)pbuf;

    float eb[CH], en[CH];
    int mb, mn = 0;
#pragma unroll
    for (int k = 0; k < CH; ++k) { eb[k] = eptr[k * T]; en[k] = 0.f; }
    mb = mptr[lane & (CH - 1)];

    float sc = 0.f;
    for (int c = 0; c < 64; ++c) {
        unsigned long long kb = __ballot(mb > 0);
        if (c < 63) {
            const float* ep2 = eptr + (c + 1) * CH * T;
#pragma unroll
            for (int k = 0; k < CH; ++k) en[k] = ep2[k * T];
            mn = mptr[(c + 1) * CH + (lane & (CH - 1))];
        }
#pragma unroll
        for (int s = 0; s < CH; ++s) {
            pbuf[lane] = sc;
            __asm__ volatile("s_waitcnt lgkmcnt(0)" ::: "memory");
            float m = -1e30f;
#pragma unroll
            for (int q = 0; q < PAD / 4; ++q) {
                float4 v4 = pb4[q];
                float ca = v4.x + Tcol[q * 4 + 0];
                float cb = v4.y + Tcol[q * 4 + 1];
                float cc = v4.z + Tcol[q * 4 + 2];
                float cd = v4.w + Tcol[q * 4 + 3];
                m = fmaxf(m, fmaxf(ca, cb));   // -> v_max3
                m = fmaxf(m, fmaxf(cc, cd));
            }
            float nxt = m + eb[s];
            bool keep = (kb >> s) & 1ULL;
            bool first = (c == 0) && (s == 0);
            sc = first ? (sjj + eb[0]) : (keep ? nxt : sc);
            if (lane < T) sptr[(size_t)(c * CH + s) * T] = sc;
        }
#pragma unroll
        for (int k = 0; k < CH; ++k) eb[k] = en[k];
        mb = mn;
    }
}

__global__ __launch_bounds__(64) void scan_kernel(
    const float* tagL, const float* posL, const int* mask,
    const int* tgT, const int* tgP,
    const float* startT, const float* transT, const float* endT,
    const float* startP, const float* transP, const float* endP,
    float* scoreT, float* scoreP,
    float* denT, float* denP, float* numT, float* numP)
{
    __shared__ __align__(16) float pbuf[64];
    int bid = blockIdx.x;
    if (bid < 64)
        vit_fwd<NP, 48>(bid, posL, mask, startP, transP, scoreP, pbuf);
    else if (bid < 128)
        nll_scan<NP, 48>(bid - 64, posL, mask, tgP, startP, transP, endP, denP, numP, pbuf);
    else if (bid < 192)
        vit_fwd<NT, 20>(bid - 128, tagL, mask, startT, transT, scoreT, pbuf);
    else
        nll_scan<NT, 20>(bid - 192, tagL, mask, tgT, startT, transT, endT, denT, numT, pbuf);
}

// ---------------------------------------------------------------------------
// Kernel 3: recompute Viterbi backpointers massively parallel over (b,t).
// Bit-identical adds vs forward pass => identical argmax.
// ---------------------------------------------------------------------------
template <int T>
__device__ void hist_block(int b, int tc,
    const float* __restrict__ score, const int* __restrict__ mask,
    const float* __restrict__ trans, unsigned char* __restrict__ hist)
{
    const int wave = threadIdx.x >> 6;
    const int lane = threadIdx.x & 63;
    const int jj = (lane < T) ? lane : (T - 1);
    float Tcol[T];
#pragma unroll
    for (int i = 0; i < T; ++i) Tcol[i] = trans[i * T + jj];
    for (int q = 0; q < 16; ++q) {
        int t = tc * 64 + wave * 16 + q;
        if (t < 1) continue;
        int mt = mask[b * 512 + t];
        int hv;
        if (mt > 0) {
            float sv = score[((size_t)b * 512 + t - 1) * T + jj];
            float mx = -1e30f; int am = 0;
#pragma unroll
            for (int i = 0; i < T; ++i) {
                float cand = rlane(sv, i) + Tcol[i];
                bool g = cand > mx;            // strict > keeps FIRST max
                mx = g ? cand : mx;
                am = g ? i : am;
            }
            hv = am;
        } else {
            hv = jj;                           // identity when masked
        }
        if (lane < T)
            hist[((size_t)b * 512 + (t - 1)) * T + lane] = (unsigned char)hv;
    }
}

__global__ __launch_bounds__(256) void hist_kernel(
    const float* scoreT, const float* scoreP, const int* mask,
    const float* transT, const float* transP,
    unsigned char* histT, unsigned char* histP)
{
    int blk = blockIdx.x;
    if (blk < 512) hist_block<NP>(blk >> 3, blk & 7, scoreP, mask, transP, histP);
    else { blk -= 512; hist_block<NT>(blk >> 3, blk & 7, scoreT, mask, transT, histT); }
}

// ---------------------------------------------------------------------------
// Kernel 4: backtrace with pointer-jump composition (serial chain 511 -> 63).
// ---------------------------------------------------------------------------
template <int T>
__device__ void backtrace(int b, const float* __restrict__ score,
    const unsigned char* __restrict__ hist, const float* __restrict__ endv,
    float* __restrict__ outp, unsigned char* sh)
{
    unsigned char* h  = sh;                    // 512*T
    unsigned char* g2 = sh + 512 * T;          // rows 0..509
    unsigned char* g4 = sh + 1024 * T;         // 127 rows (r = 3+4*a4)
    unsigned char* g8 = sh + 1024 * T + 128 * T; // 63 rows (r = 503-8a)
    unsigned char* pr = sh + 1024 * T + 192 * T; // 512
    const int lane = threadIdx.x;

    {   // stage hist to LDS (b-stride = 512*T bytes, 16B multiple)
        const int4* src = (const int4*)(hist + (size_t)b * 512 * T);
        int4* dst = (int4*)h;
        int n16 = (512 * T) / 16;
        for (int i = lane; i < n16; i += 64) dst[i] = src[i];
    }
    __syncthreads();
    // g2[r][i] = h[r][h[r+1][i]]  (maps cur at t=r+2 -> t=r)
    for (int idx = lane; idx < 510 * T; idx += 64) {
        int r = idx / T, i = idx - r * T;
        g2[idx] = h[r * T + h[(r + 1) * T + i]];
    }
    __syncthreads();
    // g4 rows r = 3+4*a4: g4[a4][i] = g2[r][ g2[r+2][i] ]  (t=r+4 -> r)
    for (int idx = lane; idx < 127 * T; idx += 64) {
        int a4 = idx / T, i = idx - a4 * T;
        int r = 3 + 4 * a4;
        g4[idx] = g2[r * T + g2[(r + 2) * T + i]];
    }
    __syncthreads();
    // g8 rows r = 503-8a: g8[a][i] = g4row(r)[ g4row(r+4)[i] ]  (t=r+8 -> r)
    for (int idx = lane; idx < 63 * T; idx += 64) {
        int a = idx / T, i = idx - a * T;
        int r = 503 - 8 * a;
        int a4lo = (r - 3) >> 2, a4hi = (r + 1) >> 2;
        g8[idx] = g4[a4lo * T + g4[a4hi * T + i]];
    }
    // last = first-index argmax(score[511] + end)
    float v = (lane < T) ? (score[((size_t)b * 512 + 511) * T + lane] + endv[lane]) : -1e30f;
    float mx = v;
#pragma unroll
    for (int o = 32; o; o >>= 1) mx = fmaxf(mx, __shfl_xor(mx, o));
    unsigned long long bal = __ballot(v == mx);
    int cur = __ffsll(bal) - 1;
    __syncthreads();
    // phase A: serial anchor chain, 63 dependent LDS reads
    int myCur = 0;
    for (int a = 0; a < 64; ++a) {
        if (lane == a) myCur = cur;
        if (a < 63) cur = g8[a * T + cur];
    }
    // phase B: each lane fills its 8-step segment
    {
        int ta = 511 - 8 * lane;
        int j = myCur;
        pr[ta] = (unsigned char)j;
        int rlo = (lane == 63) ? 0 : (ta - 7);
        for (int r = ta - 1; r >= rlo; --r) {
            j = h[r * T + j];
            pr[r] = (unsigned char)j;
        }
    }
    __syncthreads();
    for (int k = lane; k < 512; k += 64)
        outp[(size_t)b * 512 + k] = (float)pr[k];
}

__global__ __launch_bounds__(64) void backtrace_kernel(
    const float* scoreT, const float* scoreP,
    const unsigned char* histT, const unsigned char* histP,
    const float* endT, const float* endP, float* out)
{
    __shared__ __align__(16) unsigned char sh[1216 * NP + 576];
    int blk = blockIdx.x;
    if (blk < 64) backtrace<NP>(blk, scoreP, histP, endP, out + 32768, sh);
    else backtrace<NT>(blk - 64, scoreT, histT, endT, out, sh);
}

// ---------------------------------------------------------------------------
// Kernel 5: losses = -mean(num - den)
// ---------------------------------------------------------------------------
__global__ __launch_bounds__(64) void finalize_kernel(
    const float* numT, const float* denT, const float* numP, const float* denP,
    float* out)
{
    int lane = threadIdx.x;
    float dT = numT[lane] - denT[lane];
    float dP = numP[lane] - denP[lane];
#pragma unroll
    for (int o = 32; o; o >>= 1) { dT += __shfl_xor(dT, o); dP += __shfl_xor(dP, o); }
    if (lane == 0) {
        out[65536] = -dT / 64.f;
        out[65537] = -dP / 64.f;
    }
}

// ---------------------------------------------------------------------------
extern "C" void kernel_launch(void* const* d_in, const int* in_sizes, int n_in,
                              void* d_out, int out_size, void* d_ws, size_t ws_size,
                              hipStream_t stream)
{
    const float* hidden = (const float*)d_in[0];
    const int*   mask   = (const int*)d_in[1];
    const int*   tgT    = (const int*)d_in[2];
    const int*   tgP    = (const int*)d_in[3];
    const float* Wt     = (const float*)d_in[4];
    const float* bt     = (const float*)d_in[5];
    const float* Wp     = (const float*)d_in[6];
    const float* bp     = (const float*)d_in[7];
    const float* startT = (const float*)d_in[8];
    const float* transT = (const float*)d_in[9];
    const float* endT   = (const float*)d_in[10];
    const float* startP = (const float*)d_in[11];
    const float* transP = (const float*)d_in[12];
    const float* endP   = (const float*)d_in[13];

    float* ws     = (float*)d_ws;
    float* tagL   = ws;                         // 557056
    float* posL   = tagL + 557056;              // 1474560
    float* scoreT = posL + 1474560;             // 557056
    float* scoreP = scoreT + 557056;            // 1474560
    float* denT   = scoreP + 1474560;           // 64
    float* denP   = denT + 64;
    float* numT   = denP + 64;
    float* numP   = numT + 64;
    unsigned char* histT = (unsigned char*)(numP + 64);       // 64*512*17 B
    unsigned char* histP = histT + (size_t)64 * 512 * NT;     // 64*512*45 B
    float* out = (float*)d_out;

    gemm_logits<<<512, 256, 0, stream>>>(hidden, Wt, bt, Wp, bp, tagL, posL);
    scan_kernel<<<256, 64, 0, stream>>>(tagL, posL, mask, tgT, tgP,
        startT, transT, endT, startP, transP, endP,
        scoreT, scoreP, denT, denP, numT, numP);
    hist_kernel<<<1024, 256, 0, stream>>>(scoreT, scoreP, mask, transT, transP,
        histT, histP);
    backtrace_kernel<<<128, 64, 0, stream>>>(scoreT, scoreP, histT, histP,
        endT, endP, out);
    finalize_kernel<<<1, 64, 0, stream>>>(numT, denT, numP, denP, out);
}

// Round 4
// 524.851 us; speedup vs baseline: 1.1846x; 1.0063x over previous
//
#include <hip/hip_runtime.h>
#include <cmath>
#include <cstdint>
#include <cstddef>

#define NT 17
#define NP 45
#define CH 8
// B=64, S=512, H=768

__device__ __forceinline__ float rfirst(float v) {
    return __int_as_float(__builtin_amdgcn_readfirstlane(__float_as_int(v)));
}
__device__ __forceinline__ float rlane(float v, int k) {
    return __int_as_float(__builtin_amdgcn_readlane(__float_as_int(v), k));
}

// ---------------------------------------------------------------------------
// Kernel 1: logits = hidden @ [W_tag | W_pos] + bias   (f32 vector GEMM)
// ---------------------------------------------------------------------------
__global__ __launch_bounds__(256) void gemm_logits(
    const float* __restrict__ hidden, const float* __restrict__ Wt,
    const float* __restrict__ bt, const float* __restrict__ Wp,
    const float* __restrict__ bp, float* __restrict__ tagL,
    float* __restrict__ posL)
{
    __shared__ float As[32 * 68];
    __shared__ float Bs[32 * 64];
    const int tid = threadIdx.x;
    const int rg = tid >> 4;
    const int cg = tid & 15;
    const int row0 = blockIdx.x * 64;

    float acc[4][4];
#pragma unroll
    for (int a = 0; a < 4; ++a)
#pragma unroll
        for (int b = 0; b < 4; ++b) acc[a][b] = 0.f;

    for (int kc = 0; kc < 768; kc += 32) {
        __syncthreads();
#pragma unroll
        for (int it = 0; it < 2; ++it) {
            int idx = tid + it * 256;
            int r = idx >> 3, q = idx & 7;
            float4 h = *(const float4*)(hidden + (size_t)(row0 + r) * 768 + kc + q * 4);
            As[(q * 4 + 0) * 68 + r] = h.x;
            As[(q * 4 + 1) * 68 + r] = h.y;
            As[(q * 4 + 2) * 68 + r] = h.z;
            As[(q * 4 + 3) * 68 + r] = h.w;
        }
#pragma unroll
        for (int it = 0; it < 8; ++it) {
            int idx = tid + it * 256;
            int k = idx >> 6, c = idx & 63;
            float v = 0.f;
            if (c < NT) v = Wt[(kc + k) * NT + c];
            else if (c < NT + NP) v = Wp[(kc + k) * NP + (c - NT)];
            Bs[idx] = v;
        }
        __syncthreads();
#pragma unroll
        for (int kk = 0; kk < 32; ++kk) {
            float4 a4 = *(const float4*)(As + kk * 68 + rg * 4);
            float4 b4 = *(const float4*)(Bs + kk * 64 + cg * 4);
            float av[4] = {a4.x, a4.y, a4.z, a4.w};
            float bv[4] = {b4.x, b4.y, b4.z, b4.w};
#pragma unroll
            for (int jr = 0; jr < 4; ++jr)
#pragma unroll
                for (int jc = 0; jc < 4; ++jc)
                    acc[jr][jc] = fmaf(av[jr], bv[jc], acc[jr][jc]);
        }
    }
#pragma unroll
    for (int jr = 0; jr < 4; ++jr) {
        size_t r = (size_t)row0 + rg * 4 + jr;
#pragma unroll
        for (int jc = 0; jc < 4; ++jc) {
            int c = cg * 4 + jc;
            if (c < NT) tagL[r * NT + c] = acc[jr][jc] + bt[c];
            else if (c < NT + NP) posL[r * NP + (c - NT)] = acc[jr][jc] + bp[c - NT];
        }
    }
}

// ---------------------------------------------------------------------------
// Kernel 2: the four CRF scans. One wave per (b, role); 256 blocks x 64 thr.
// __launch_bounds__(64,1): single-wave blocks, 1 wave/CU resident -> let the
// allocator use up to ~512 VGPRs so Ecol/Tcol[48]+eb/en[16] live in registers
// (at the default occupancy-targeted 64 VGPRs they spilled to scratch and the
// reloads sat in the critical chain of all 512 steps).
// ---------------------------------------------------------------------------
template <int T, int PAD>
__device__ void nll_scan(int b,
    const float* __restrict__ logits, const int* __restrict__ mask,
    const int* __restrict__ targ, const float* __restrict__ start,
    const float* __restrict__ trans, const float* __restrict__ endv,
    float* __restrict__ den, float* __restrict__ num, float* pbuf)
{
    const int lane = threadIdx.x;
    const int jj = (lane < T) ? lane : (T - 1);
    float Ecol[PAD];
#pragma unroll
    for (int i = 0; i < PAD; ++i) Ecol[i] = (i < T) ? __expf(trans[i * T + jj]) : 0.f;
    const float sjj = start[jj];
    const float* eptr = logits + (size_t)b * 512 * T + jj;
    const int* mptr = mask + b * 512;
    const float4* pb4 = (const float4*)pbuf;

    float eb[CH], en[CH];
    int mb, mn = 0;
#pragma unroll
    for (int k = 0; k < CH; ++k) { eb[k] = eptr[k * T]; en[k] = 0.f; }
    mb = mptr[lane & (CH - 1)];

    float sc = 0.f;
    for (int c = 0; c < 64; ++c) {
        unsigned long long kb = __ballot(mb > 0);
        if (c < 63) {
            const float* ep2 = eptr + (c + 1) * CH * T;
#pragma unroll
            for (int k = 0; k < CH; ++k) en[k] = ep2[k * T];
            mn = mptr[(c + 1) * CH + (lane & (CH - 1))];
        }
#pragma unroll
        for (int s = 0; s < CH; ++s) {
            float c0 = rfirst(sc);
            float p = __expf(sc - c0);
            pbuf[lane] = (lane < T) ? p : 0.f;
            __asm__ volatile("s_waitcnt lgkmcnt(0)" ::: "memory");
            float d0 = 0.f, d1 = 0.f, d2 = 0.f, d3 = 0.f;
#pragma unroll
            for (int q = 0; q < PAD / 4; ++q) {
                float4 v4 = pb4[q];
                d0 = fmaf(v4.x, Ecol[q * 4 + 0], d0);
                d1 = fmaf(v4.y, Ecol[q * 4 + 1], d1);
                d2 = fmaf(v4.z, Ecol[q * 4 + 2], d2);
                d3 = fmaf(v4.w, Ecol[q * 4 + 3], d3);
            }
            float nxt = __logf((d0 + d1) + (d2 + d3)) + c0 + eb[s];
            bool keep = (kb >> s) & 1ULL;
            bool first = (c == 0) && (s == 0);
            sc = first ? (sjj + eb[0]) : (keep ? nxt : sc);
        }
#pragma unroll
        for (int k = 0; k < CH; ++k) eb[k] = en[k];
        mb = mn;
    }
    // denominator
    float v = (lane < T) ? (sc + endv[lane]) : -1e30f;
    float m = v;
#pragma unroll
    for (int o = 32; o; o >>= 1) m = fmaxf(m, __shfl_xor(m, o));
    float se = (lane < T) ? __expf(v - m) : 0.f;
#pragma unroll
    for (int o = 32; o; o >>= 1) se += __shfl_xor(se, o);
    if (lane == 0) den[b] = m + __logf(se);

    // numerator (raw logits; lse cancels in num-den)
    float part = 0.f; int Lc = 0;
    for (int t = lane; t < 512; t += 64) {
        int mt = mask[b * 512 + t];
        Lc += (mt > 0);
        if (t >= 1 && mt > 0) {
            int tg = targ[b * 512 + t];
            int pg = targ[b * 512 + t - 1];
            part += trans[pg * T + tg] + logits[((size_t)b * 512 + t) * T + tg];
        }
    }
#pragma unroll
    for (int o = 32; o; o >>= 1) { part += __shfl_xor(part, o); Lc += __shfl_xor(Lc, o); }
    if (lane == 0) {
        int t0g = targ[b * 512];
        num[b] = start[t0g] + logits[(size_t)b * 512 * T + t0g]
               + part + endv[targ[b * 512 + Lc - 1]];
    }
}

// Viterbi forward, max only; stores score vectors for later argmax recompute.
template <int T, int PAD>
__device__ void vit_fwd(int b,
    const float* __restrict__ logits, const int* __restrict__ mask,
    const float* __restrict__ start, const float* __restrict__ trans,
    float* __restrict__ score, float* pbuf)
{
    const int lane = threadIdx.x;
    const int jj = (lane < T) ? lane : (T - 1);
    float Tcol[PAD];
#pragma unroll
    for (int i = 0; i < PAD; ++i) Tcol[i] = (i < T) ? trans[i * T + jj] : -1e30f;
    const float sjj = start[jj];
    const float* eptr = logits + (size_t)b * 512 * T + jj;
    const int* mptr = mask + b * 512;
    float* sptr = score + (size_t)b * 512 * T + lane;
    const float4* pb4 = (const float4*)pbuf;

    float eb[CH], en[CH];
    int mb, mn = 0;
#pragma unroll
    for (int k = 0; k < CH; ++k) { eb[k] = eptr[k * T]; en[k] = 0.f; }
    mb = mptr[lane & (CH - 1)];

    float sc = 0.f;
    for (int c = 0; c < 64; ++c) {
        unsigned long long kb = __ballot(mb > 0);
        if (c < 63) {
            const float* ep2 = eptr + (c + 1) * CH * T;
#pragma unroll
            for (int k = 0; k < CH; ++k) en[k] = ep2[k * T];
            mn = mptr[(c + 1) * CH + (lane & (CH - 1))];
        }
#pragma unroll
        for (int s = 0; s < CH; ++s) {
            pbuf[lane] = sc;
            __asm__ volatile("s_waitcnt lgkmcnt(0)" ::: "memory");
            float m = -1e30f;
#pragma unroll
            for (int q = 0; q < PAD / 4; ++q) {
                float4 v4 = pb4[q];
                float ca = v4.x + Tcol[q * 4 + 0];
                float cb = v4.y + Tcol[q * 4 + 1];
                float cc = v4.z + Tcol[q * 4 + 2];
                float cd = v4.w + Tcol[q * 4 + 3];
                m = fmaxf(m, fmaxf(ca, cb));   // -> v_max3
                m = fmaxf(m, fmaxf(cc, cd));
            }
            float nxt = m + eb[s];
            bool keep = (kb >> s) & 1ULL;
            bool first = (c == 0) && (s == 0);
            sc = first ? (sjj + eb[0]) : (keep ? nxt : sc);
            if (lane < T) sptr[(size_t)(c * CH + s) * T] = sc;
        }
#pragma unroll
        for (int k = 0; k < CH; ++k) eb[k] = en[k];
        mb = mn;
    }
}

__global__ __launch_bounds__(64, 1) void scan_kernel(
    const float* tagL, const float* posL, const int* mask,
    const int* tgT, const int* tgP,
    const float* startT, const float* transT, const float* endT,
    const float* startP, const float* transP, const float* endP,
    float* scoreT, float* scoreP,
    float* denT, float* denP, float* numT, float* numP)
{
    __shared__ __align__(16) float pbuf[64];
    int bid = blockIdx.x;
    if (bid < 64)
        vit_fwd<NP, 48>(bid, posL, mask, startP, transP, scoreP, pbuf);
    else if (bid < 128)
        nll_scan<NP, 48>(bid - 64, posL, mask, tgP, startP, transP, endP, denP, numP, pbuf);
    else if (bid < 192)
        vit_fwd<NT, 20>(bid - 128, tagL, mask, startT, transT, scoreT, pbuf);
    else
        nll_scan<NT, 20>(bid - 192, tagL, mask, tgT, startT, transT, endT, denT, numT, pbuf);
}

// ---------------------------------------------------------------------------
// Kernel 3: recompute Viterbi backpointers massively parallel over (b,t).
// Bit-identical adds vs forward pass => identical argmax.
// ---------------------------------------------------------------------------
template <int T>
__device__ void hist_block(int b, int tc,
    const float* __restrict__ score, const int* __restrict__ mask,
    const float* __restrict__ trans, unsigned char* __restrict__ hist)
{
    const int wave = threadIdx.x >> 6;
    const int lane = threadIdx.x & 63;
    const int jj = (lane < T) ? lane : (T - 1);
    float Tcol[T];
#pragma unroll
    for (int i = 0; i < T; ++i) Tcol[i] = trans[i * T + jj];
    for (int q = 0; q < 16; ++q) {
        int t = tc * 64 + wave * 16 + q;
        if (t < 1) continue;
        int mt = mask[b * 512 + t];
        int hv;
        if (mt > 0) {
            float sv = score[((size_t)b * 512 + t - 1) * T + jj];
            float mx = -1e30f; int am = 0;
#pragma unroll
            for (int i = 0; i < T; ++i) {
                float cand = rlane(sv, i) + Tcol[i];
                bool g = cand > mx;            // strict > keeps FIRST max
                mx = g ? cand : mx;
                am = g ? i : am;
            }
            hv = am;
        } else {
            hv = jj;                           // identity when masked
        }
        if (lane < T)
            hist[((size_t)b * 512 + (t - 1)) * T + lane] = (unsigned char)hv;
    }
}

__global__ __launch_bounds__(256) void hist_kernel(
    const float* scoreT, const float* scoreP, const int* mask,
    const float* transT, const float* transP,
    unsigned char* histT, unsigned char* histP)
{
    int blk = blockIdx.x;
    if (blk < 512) hist_block<NP>(blk >> 3, blk & 7, scoreP, mask, transP, histP);
    else { blk -= 512; hist_block<NT>(blk >> 3, blk & 7, scoreT, mask, transT, histT); }
}

// ---------------------------------------------------------------------------
// Kernel 4: backtrace with pointer-jump composition (serial chain 511 -> 63).
// ---------------------------------------------------------------------------
template <int T>
__device__ void backtrace(int b, const float* __restrict__ score,
    const unsigned char* __restrict__ hist, const float* __restrict__ endv,
    float* __restrict__ outp, unsigned char* sh)
{
    unsigned char* h  = sh;                    // 512*T
    unsigned char* g2 = sh + 512 * T;          // rows 0..509
    unsigned char* g4 = sh + 1024 * T;         // 127 rows (r = 3+4*a4)
    unsigned char* g8 = sh + 1024 * T + 128 * T; // 63 rows (r = 503-8a)
    unsigned char* pr = sh + 1024 * T + 192 * T; // 512
    const int lane = threadIdx.x;

    {   // stage hist to LDS (b-stride = 512*T bytes, 16B multiple)
        const int4* src = (const int4*)(hist + (size_t)b * 512 * T);
        int4* dst = (int4*)h;
        int n16 = (512 * T) / 16;
        for (int i = lane; i < n16; i += 64) dst[i] = src[i];
    }
    __syncthreads();
    // g2[r][i] = h[r][h[r+1][i]]  (maps cur at t=r+2 -> t=r)
    for (int idx = lane; idx < 510 * T; idx += 64) {
        int r = idx / T, i = idx - r * T;
        g2[idx] = h[r * T + h[(r + 1) * T + i]];
    }
    __syncthreads();
    // g4 rows r = 3+4*a4: g4[a4][i] = g2[r][ g2[r+2][i] ]  (t=r+4 -> r)
    for (int idx = lane; idx < 127 * T; idx += 64) {
        int a4 = idx / T, i = idx - a4 * T;
        int r = 3 + 4 * a4;
        g4[idx] = g2[r * T + g2[(r + 2) * T + i]];
    }
    __syncthreads();
    // g8 rows r = 503-8a: g8[a][i] = g4row(r)[ g4row(r+4)[i] ]  (t=r+8 -> r)
    for (int idx = lane; idx < 63 * T; idx += 64) {
        int a = idx / T, i = idx - a * T;
        int r = 503 - 8 * a;
        int a4lo = (r - 3) >> 2, a4hi = (r + 1) >> 2;
        g8[idx] = g4[a4lo * T + g4[a4hi * T + i]];
    }
    // last = first-index argmax(score[511] + end)
    float v = (lane < T) ? (score[((size_t)b * 512 + 511) * T + lane] + endv[lane]) : -1e30f;
    float mx = v;
#pragma unroll
    for (int o = 32; o; o >>= 1) mx = fmaxf(mx, __shfl_xor(mx, o));
    unsigned long long bal = __ballot(v == mx);
    int cur = __ffsll(bal) - 1;
    __syncthreads();
    // phase A: serial anchor chain, 63 dependent LDS reads
    int myCur = 0;
    for (int a = 0; a < 64; ++a) {
        if (lane == a) myCur = cur;
        if (a < 63) cur = g8[a * T + cur];
    }
    // phase B: each lane fills its 8-step segment
    {
        int ta = 511 - 8 * lane;
        int j = myCur;
        pr[ta] = (unsigned char)j;
        int rlo = (lane == 63) ? 0 : (ta - 7);
        for (int r = ta - 1; r >= rlo; --r) {
            j = h[r * T + j];
            pr[r] = (unsigned char)j;
        }
    }
    __syncthreads();
    for (int k = lane; k < 512; k += 64)
        outp[(size_t)b * 512 + k] = (float)pr[k];
}

__global__ __launch_bounds__(64, 1) void backtrace_kernel(
    const float* scoreT, const float* scoreP,
    const unsigned char* histT, const unsigned char* histP,
    const float* endT, const float* endP, float* out)
{
    __shared__ __align__(16) unsigned char sh[1216 * NP + 576];
    int blk = blockIdx.x;
    if (blk < 64) backtrace<NP>(blk, scoreP, histP, endP, out + 32768, sh);
    else backtrace<NT>(blk - 64, scoreT, histT, endT, out, sh);
}

// ---------------------------------------------------------------------------
// Kernel 5: losses = -mean(num - den)
// ---------------------------------------------------------------------------
__global__ __launch_bounds__(64) void finalize_kernel(
    const float* numT, const float* denT, const float* numP, const float* denP,
    float* out)
{
    int lane = threadIdx.x;
    float dT = numT[lane] - denT[lane];
    float dP = numP[lane] - denP[lane];
#pragma unroll
    for (int o = 32; o; o >>= 1) { dT += __shfl_xor(dT, o); dP += __shfl_xor(dP, o); }
    if (lane == 0) {
        out[65536] = -dT / 64.f;
        out[65537] = -dP / 64.f;
    }
}

// ---------------------------------------------------------------------------
extern "C" void kernel_launch(void* const* d_in, const int* in_sizes, int n_in,
                              void* d_out, int out_size, void* d_ws, size_t ws_size,
                              hipStream_t stream)
{
    const float* hidden = (const float*)d_in[0];
    const int*   mask   = (const int*)d_in[1];
    const int*   tgT    = (const int*)d_in[2];
    const int*   tgP    = (const int*)d_in[3];
    const float* Wt     = (const float*)d_in[4];
    const float* bt     = (const float*)d_in[5];
    const float* Wp     = (const float*)d_in[6];
    const float* bp     = (const float*)d_in[7];
    const float* startT = (const float*)d_in[8];
    const float* transT = (const float*)d_in[9];
    const float* endT   = (const float*)d_in[10];
    const float* startP = (const float*)d_in[11];
    const float* transP = (const float*)d_in[12];
    const float* endP   = (const float*)d_in[13];

    float* ws     = (float*)d_ws;
    float* tagL   = ws;                         // 557056
    float* posL   = tagL + 557056;              // 1474560
    float* scoreT = posL + 1474560;             // 557056
    float* scoreP = scoreT + 557056;            // 1474560
    float* denT   = scoreP + 1474560;           // 64
    float* denP   = denT + 64;
    float* numT   = denP + 64;
    float* numP   = numT + 64;
    unsigned char* histT = (unsigned char*)(numP + 64);       // 64*512*17 B
    unsigned char* histP = histT + (size_t)64 * 512 * NT;     // 64*512*45 B
    float* out = (float*)d_out;

    gemm_logits<<<512, 256, 0, stream>>>(hidden, Wt, bt, Wp, bp, tagL, posL);
    scan_kernel<<<256, 64, 0, stream>>>(tagL, posL, mask, tgT, tgP,
        startT, transT, endT, startP, transP, endP,
        scoreT, scoreP, denT, denP, numT, numP);
    hist_kernel<<<1024, 256, 0, stream>>>(scoreT, scoreP, mask, transT, transP,
        histT, histP);
    backtrace_kernel<<<128, 64, 0, stream>>>(scoreT, scoreP, histT, histP,
        endT, endP, out);
    finalize_kernel<<<1, 64, 0, stream>>>(numT, denT, numP, denP, out);
}

// Round 5
// 515.865 us; speedup vs baseline: 1.2052x; 1.0174x over previous
//
#include <hip/hip_runtime.h>
#include <cmath>
#include <cstdint>
#include <cstddef>

#define NT 17
#define NP 45
#define CH 8
// B=64, S=512, H=768

__device__ __forceinline__ float rlane(float v, int k) {
    return __int_as_float(__builtin_amdgcn_readlane(__float_as_int(v), k));
}

// ---------------------------------------------------------------------------
// Kernel 1: logits = hidden @ [W_tag | W_pos] + bias   (f32 vector GEMM)
// ---------------------------------------------------------------------------
__global__ __launch_bounds__(256) void gemm_logits(
    const float* __restrict__ hidden, const float* __restrict__ Wt,
    const float* __restrict__ bt, const float* __restrict__ Wp,
    const float* __restrict__ bp, float* __restrict__ tagL,
    float* __restrict__ posL)
{
    __shared__ float As[32 * 68];
    __shared__ float Bs[32 * 64];
    const int tid = threadIdx.x;
    const int rg = tid >> 4;
    const int cg = tid & 15;
    const int row0 = blockIdx.x * 64;

    float acc[4][4];
#pragma unroll
    for (int a = 0; a < 4; ++a)
#pragma unroll
        for (int b = 0; b < 4; ++b) acc[a][b] = 0.f;

    for (int kc = 0; kc < 768; kc += 32) {
        __syncthreads();
#pragma unroll
        for (int it = 0; it < 2; ++it) {
            int idx = tid + it * 256;
            int r = idx >> 3, q = idx & 7;
            float4 h = *(const float4*)(hidden + (size_t)(row0 + r) * 768 + kc + q * 4);
            As[(q * 4 + 0) * 68 + r] = h.x;
            As[(q * 4 + 1) * 68 + r] = h.y;
            As[(q * 4 + 2) * 68 + r] = h.z;
            As[(q * 4 + 3) * 68 + r] = h.w;
        }
#pragma unroll
        for (int it = 0; it < 8; ++it) {
            int idx = tid + it * 256;
            int k = idx >> 6, c = idx & 63;
            float v = 0.f;
            if (c < NT) v = Wt[(kc + k) * NT + c];
            else if (c < NT + NP) v = Wp[(kc + k) * NP + (c - NT)];
            Bs[idx] = v;
        }
        __syncthreads();
#pragma unroll
        for (int kk = 0; kk < 32; ++kk) {
            float4 a4 = *(const float4*)(As + kk * 68 + rg * 4);
            float4 b4 = *(const float4*)(Bs + kk * 64 + cg * 4);
            float av[4] = {a4.x, a4.y, a4.z, a4.w};
            float bv[4] = {b4.x, b4.y, b4.z, b4.w};
#pragma unroll
            for (int jr = 0; jr < 4; ++jr)
#pragma unroll
                for (int jc = 0; jc < 4; ++jc)
                    acc[jr][jc] = fmaf(av[jr], bv[jc], acc[jr][jc]);
        }
    }
#pragma unroll
    for (int jr = 0; jr < 4; ++jr) {
        size_t r = (size_t)row0 + rg * 4 + jr;
#pragma unroll
        for (int jc = 0; jc < 4; ++jc) {
            int c = cg * 4 + jc;
            if (c < NT) tagL[r * NT + c] = acc[jr][jc] + bt[c];
            else if (c < NT + NP) posL[r * NP + (c - NT)] = acc[jr][jc] + bp[c - NT];
        }
    }
}

// ---------------------------------------------------------------------------
// Kernel 2: the four CRF scans. One wave per (b, role); 256 blocks x 64 thr.
// DS ops within a wave complete in order -> ds_write followed by ds_read of
// the same buffer needs NO intervening waitcnt; compiler auto-waits before
// first use. NLL runs in LINEAR space (f = exp(e) precomputed off-chain per
// chunk; exact power-of-2 rescale per chunk) so the serial chain has no
// exp/log at all.
// ---------------------------------------------------------------------------
template <int T, int PAD>
__device__ void nll_scan(int b,
    const float* __restrict__ logits, const int* __restrict__ mask,
    const int* __restrict__ targ, const float* __restrict__ start,
    const float* __restrict__ trans, const float* __restrict__ endv,
    float* __restrict__ den, float* __restrict__ num, float* pbuf)
{
    const int lane = threadIdx.x;
    const int jj = (lane < T) ? lane : (T - 1);
    float Ecol[PAD];
#pragma unroll
    for (int i = 0; i < PAD; ++i) Ecol[i] = (i < T) ? __expf(trans[i * T + jj]) : 0.f;
    const float esjj = __expf(start[jj]);
    const float* eptr = logits + (size_t)b * 512 * T + jj;
    const int* mptr = mask + b * 512;
    const float4* pb4 = (const float4*)pbuf;

    float eb[CH], en[CH], fb[CH];
    int mb, mn = 0;
#pragma unroll
    for (int k = 0; k < CH; ++k) { eb[k] = eptr[k * T]; en[k] = 0.f; }
    mb = mptr[lane & (CH - 1)];

    float a = 0.f;
    int excorr = 0;
    for (int c = 0; c < 64; ++c) {
        unsigned long long kb = __ballot(mb > 0);
        if (c < 63) {
            const float* ep2 = eptr + (c + 1) * CH * T;
#pragma unroll
            for (int k = 0; k < CH; ++k) en[k] = ep2[k * T];
            mn = mptr[(c + 1) * CH + (lane & (CH - 1))];
        }
#pragma unroll
        for (int k = 0; k < CH; ++k) fb[k] = __expf(eb[k]);   // off-chain
#pragma unroll
        for (int s = 0; s < CH; ++s) {
            pbuf[lane] = a;                    // ds_write; reads below are
            float d0 = 0.f, d1 = 0.f, d2 = 0.f, d3 = 0.f;  // in-order after it
#pragma unroll
            for (int q = 0; q < PAD / 4; ++q) {
                float4 v4 = pb4[q];
                d0 = fmaf(v4.x, Ecol[q * 4 + 0], d0);
                d1 = fmaf(v4.y, Ecol[q * 4 + 1], d1);
                d2 = fmaf(v4.z, Ecol[q * 4 + 2], d2);
                d3 = fmaf(v4.w, Ecol[q * 4 + 3], d3);
            }
            float cand = ((d0 + d1) + (d2 + d3)) * fb[s];
            bool keep = (kb >> s) & 1ULL;
            bool first = (c == 0) && (s == 0);
            a = first ? (esjj * fb[0]) : (keep ? cand : a);
        }
        // exact power-of-2 rescale (avoids overflow; ~10^24 worst per chunk)
        float m = a;
#pragma unroll
        for (int o = 32; o; o >>= 1) m = fmaxf(m, __shfl_xor(m, o));
        int ex;
        (void)frexpf(m, &ex);
        a *= ldexpf(1.0f, -ex);
        excorr += ex;
#pragma unroll
        for (int k = 0; k < CH; ++k) eb[k] = en[k];
        mb = mn;
    }
    // denominator: log(sum_j a_j * exp(end_j)) + excorr*ln2
    float term = (lane < T) ? a * __expf(endv[lane]) : 0.f;
#pragma unroll
    for (int o = 32; o; o >>= 1) term += __shfl_xor(term, o);
    if (lane == 0) den[b] = __logf(term) + (float)excorr * 0.69314718056f;

    // numerator (raw logits; lse cancels in num-den)
    float part = 0.f; int Lc = 0;
    for (int t = lane; t < 512; t += 64) {
        int mt = mask[b * 512 + t];
        Lc += (mt > 0);
        if (t >= 1 && mt > 0) {
            int tg = targ[b * 512 + t];
            int pg = targ[b * 512 + t - 1];
            part += trans[pg * T + tg] + logits[((size_t)b * 512 + t) * T + tg];
        }
    }
#pragma unroll
    for (int o = 32; o; o >>= 1) { part += __shfl_xor(part, o); Lc += __shfl_xor(Lc, o); }
    if (lane == 0) {
        int t0g = targ[b * 512];
        num[b] = start[t0g] + logits[(size_t)b * 512 * T + t0g]
               + part + endv[targ[b * 512 + Lc - 1]];
    }
}

// Viterbi forward, max only; stores score vectors for later argmax recompute.
template <int T, int PAD>
__device__ void vit_fwd(int b,
    const float* __restrict__ logits, const int* __restrict__ mask,
    const float* __restrict__ start, const float* __restrict__ trans,
    float* __restrict__ score, float* pbuf)
{
    const int lane = threadIdx.x;
    const int jj = (lane < T) ? lane : (T - 1);
    float Tcol[PAD];
#pragma unroll
    for (int i = 0; i < PAD; ++i) Tcol[i] = (i < T) ? trans[i * T + jj] : -1e30f;
    const float sjj = start[jj];
    const float* eptr = logits + (size_t)b * 512 * T + jj;
    const int* mptr = mask + b * 512;
    float* sptr = score + (size_t)b * 512 * T + lane;
    const float4* pb4 = (const float4*)pbuf;

    float eb[CH], en[CH];
    int mb, mn = 0;
#pragma unroll
    for (int k = 0; k < CH; ++k) { eb[k] = eptr[k * T]; en[k] = 0.f; }
    mb = mptr[lane & (CH - 1)];

    float sc = 0.f;
    for (int c = 0; c < 64; ++c) {
        unsigned long long kb = __ballot(mb > 0);
        if (c < 63) {
            const float* ep2 = eptr + (c + 1) * CH * T;
#pragma unroll
            for (int k = 0; k < CH; ++k) en[k] = ep2[k * T];
            mn = mptr[(c + 1) * CH + (lane & (CH - 1))];
        }
#pragma unroll
        for (int s = 0; s < CH; ++s) {
            pbuf[lane] = sc;                   // in-order DS: no waitcnt needed
            float m = -1e30f;
#pragma unroll
            for (int q = 0; q < PAD / 4; ++q) {
                float4 v4 = pb4[q];
                float ca = v4.x + Tcol[q * 4 + 0];
                float cb = v4.y + Tcol[q * 4 + 1];
                float cc = v4.z + Tcol[q * 4 + 2];
                float cd = v4.w + Tcol[q * 4 + 3];
                m = fmaxf(m, fmaxf(ca, cb));   // -> v_max3
                m = fmaxf(m, fmaxf(cc, cd));
            }
            float nxt = m + eb[s];
            bool keep = (kb >> s) & 1ULL;
            bool first = (c == 0) && (s == 0);
            sc = first ? (sjj + eb[0]) : (keep ? nxt : sc);
            if (lane < T) sptr[(size_t)(c * CH + s) * T] = sc;
        }
#pragma unroll
        for (int k = 0; k < CH; ++k) eb[k] = en[k];
        mb = mn;
    }
}

__global__ __launch_bounds__(64, 1) void scan_kernel(
    const float* tagL, const float* posL, const int* mask,
    const int* tgT, const int* tgP,
    const float* startT, const float* transT, const float* endT,
    const float* startP, const float* transP, const float* endP,
    float* scoreT, float* scoreP,
    float* denT, float* denP, float* numT, float* numP)
{
    __shared__ __align__(16) float pbuf[64];
    int bid = blockIdx.x;
    if (bid < 64)
        vit_fwd<NP, 48>(bid, posL, mask, startP, transP, scoreP, pbuf);
    else if (bid < 128)
        nll_scan<NP, 48>(bid - 64, posL, mask, tgP, startP, transP, endP, denP, numP, pbuf);
    else if (bid < 192)
        vit_fwd<NT, 20>(bid - 128, tagL, mask, startT, transT, scoreT, pbuf);
    else
        nll_scan<NT, 20>(bid - 192, tagL, mask, tgT, startT, transT, endT, denT, numT, pbuf);
}

// ---------------------------------------------------------------------------
// Kernel 3: recompute Viterbi backpointers massively parallel over (b,t).
// Bit-identical adds vs forward pass => identical argmax.
// ---------------------------------------------------------------------------
template <int T>
__device__ void hist_block(int b, int tc,
    const float* __restrict__ score, const int* __restrict__ mask,
    const float* __restrict__ trans, unsigned char* __restrict__ hist)
{
    const int wave = threadIdx.x >> 6;
    const int lane = threadIdx.x & 63;
    const int jj = (lane < T) ? lane : (T - 1);
    float Tcol[T];
#pragma unroll
    for (int i = 0; i < T; ++i) Tcol[i] = trans[i * T + jj];
    for (int q = 0; q < 16; ++q) {
        int t = tc * 64 + wave * 16 + q;
        if (t < 1) continue;
        int mt = mask[b * 512 + t];
        int hv;
        if (mt > 0) {
            float sv = score[((size_t)b * 512 + t - 1) * T + jj];
            float mx = -1e30f; int am = 0;
#pragma unroll
            for (int i = 0; i < T; ++i) {
                float cand = rlane(sv, i) + Tcol[i];
                bool g = cand > mx;            // strict > keeps FIRST max
                mx = g ? cand : mx;
                am = g ? i : am;
            }
            hv = am;
        } else {
            hv = jj;                           // identity when masked
        }
        if (lane < T)
            hist[((size_t)b * 512 + (t - 1)) * T + lane] = (unsigned char)hv;
    }
}

__global__ __launch_bounds__(256) void hist_kernel(
    const float* scoreT, const float* scoreP, const int* mask,
    const float* transT, const float* transP,
    unsigned char* histT, unsigned char* histP)
{
    int blk = blockIdx.x;
    if (blk < 512) hist_block<NP>(blk >> 3, blk & 7, scoreP, mask, transP, histP);
    else { blk -= 512; hist_block<NT>(blk >> 3, blk & 7, scoreT, mask, transT, histT); }
}

// ---------------------------------------------------------------------------
// Kernel 4: backtrace with pointer-jump composition (serial chain 511 -> 63).
// ---------------------------------------------------------------------------
template <int T>
__device__ void backtrace(int b, const float* __restrict__ score,
    const unsigned char* __restrict__ hist, const float* __restrict__ endv,
    float* __restrict__ outp, unsigned char* sh)
{
    unsigned char* h  = sh;                    // 512*T
    unsigned char* g2 = sh + 512 * T;          // rows 0..509
    unsigned char* g4 = sh + 1024 * T;         // 127 rows (r = 3+4*a4)
    unsigned char* g8 = sh + 1024 * T + 128 * T; // 63 rows (r = 503-8a)
    unsigned char* pr = sh + 1024 * T + 192 * T; // 512
    const int lane = threadIdx.x;

    {   // stage hist to LDS (b-stride = 512*T bytes, 16B multiple)
        const int4* src = (const int4*)(hist + (size_t)b * 512 * T);
        int4* dst = (int4*)h;
        int n16 = (512 * T) / 16;
        for (int i = lane; i < n16; i += 64) dst[i] = src[i];
    }
    __syncthreads();
    // g2[r][i] = h[r][h[r+1][i]]  (maps cur at t=r+2 -> t=r)
    for (int idx = lane; idx < 510 * T; idx += 64) {
        int r = idx / T, i = idx - r * T;
        g2[idx] = h[r * T + h[(r + 1) * T + i]];
    }
    __syncthreads();
    // g4 rows r = 3+4*a4: g4[a4][i] = g2[r][ g2[r+2][i] ]  (t=r+4 -> r)
    for (int idx = lane; idx < 127 * T; idx += 64) {
        int a4 = idx / T, i = idx - a4 * T;
        int r = 3 + 4 * a4;
        g4[idx] = g2[r * T + g2[(r + 2) * T + i]];
    }
    __syncthreads();
    // g8 rows r = 503-8a: g8[a][i] = g4row(r)[ g4row(r+4)[i] ]  (t=r+8 -> r)
    for (int idx = lane; idx < 63 * T; idx += 64) {
        int a = idx / T, i = idx - a * T;
        int r = 503 - 8 * a;
        int a4lo = (r - 3) >> 2, a4hi = (r + 1) >> 2;
        g8[idx] = g4[a4lo * T + g4[a4hi * T + i]];
    }
    // last = first-index argmax(score[511] + end)
    float v = (lane < T) ? (score[((size_t)b * 512 + 511) * T + lane] + endv[lane]) : -1e30f;
    float mx = v;
#pragma unroll
    for (int o = 32; o; o >>= 1) mx = fmaxf(mx, __shfl_xor(mx, o));
    unsigned long long bal = __ballot(v == mx);
    int cur = __ffsll(bal) - 1;
    __syncthreads();
    // phase A: serial anchor chain, 63 dependent LDS reads
    int myCur = 0;
    for (int a = 0; a < 64; ++a) {
        if (lane == a) myCur = cur;
        if (a < 63) cur = g8[a * T + cur];
    }
    // phase B: each lane fills its 8-step segment
    {
        int ta = 511 - 8 * lane;
        int j = myCur;
        pr[ta] = (unsigned char)j;
        int rlo = (lane == 63) ? 0 : (ta - 7);
        for (int r = ta - 1; r >= rlo; --r) {
            j = h[r * T + j];
            pr[r] = (unsigned char)j;
        }
    }
    __syncthreads();
    for (int k = lane; k < 512; k += 64)
        outp[(size_t)b * 512 + k] = (float)pr[k];
}

__global__ __launch_bounds__(64, 1) void backtrace_kernel(
    const float* scoreT, const float* scoreP,
    const unsigned char* histT, const unsigned char* histP,
    const float* endT, const float* endP, float* out)
{
    __shared__ __align__(16) unsigned char sh[1216 * NP + 576];
    int blk = blockIdx.x;
    if (blk < 64) backtrace<NP>(blk, scoreP, histP, endP, out + 32768, sh);
    else backtrace<NT>(blk - 64, scoreT, histT, endT, out, sh);
}

// ---------------------------------------------------------------------------
// Kernel 5: losses = -mean(num - den)
// ---------------------------------------------------------------------------
__global__ __launch_bounds__(64) void finalize_kernel(
    const float* numT, const float* denT, const float* numP, const float* denP,
    float* out)
{
    int lane = threadIdx.x;
    float dT = numT[lane] - denT[lane];
    float dP = numP[lane] - denP[lane];
#pragma unroll
    for (int o = 32; o; o >>= 1) { dT += __shfl_xor(dT, o); dP += __shfl_xor(dP, o); }
    if (lane == 0) {
        out[65536] = -dT / 64.f;
        out[65537] = -dP / 64.f;
    }
}

// ---------------------------------------------------------------------------
extern "C" void kernel_launch(void* const* d_in, const int* in_sizes, int n_in,
                              void* d_out, int out_size, void* d_ws, size_t ws_size,
                              hipStream_t stream)
{
    const float* hidden = (const float*)d_in[0];
    const int*   mask   = (const int*)d_in[1];
    const int*   tgT    = (const int*)d_in[2];
    const int*   tgP    = (const int*)d_in[3];
    const float* Wt     = (const float*)d_in[4];
    const float* bt     = (const float*)d_in[5];
    const float* Wp     = (const float*)d_in[6];
    const float* bp     = (const float*)d_in[7];
    const float* startT = (const float*)d_in[8];
    const float* transT = (const float*)d_in[9];
    const float* endT   = (const float*)d_in[10];
    const float* startP = (const float*)d_in[11];
    const float* transP = (const float*)d_in[12];
    const float* endP   = (const float*)d_in[13];

    float* ws     = (float*)d_ws;
    float* tagL   = ws;                         // 557056
    float* posL   = tagL + 557056;              // 1474560
    float* scoreT = posL + 1474560;             // 557056
    float* scoreP = scoreT + 557056;            // 1474560
    float* denT   = scoreP + 1474560;           // 64
    float* denP   = denT + 64;
    float* numT   = denP + 64;
    float* numP   = numT + 64;
    unsigned char* histT = (unsigned char*)(numP + 64);       // 64*512*17 B
    unsigned char* histP = histT + (size_t)64 * 512 * NT;     // 64*512*45 B
    float* out = (float*)d_out;

    gemm_logits<<<512, 256, 0, stream>>>(hidden, Wt, bt, Wp, bp, tagL, posL);
    scan_kernel<<<256, 64, 0, stream>>>(tagL, posL, mask, tgT, tgP,
        startT, transT, endT, startP, transP, endP,
        scoreT, scoreP, denT, denP, numT, numP);
    hist_kernel<<<1024, 256, 0, stream>>>(scoreT, scoreP, mask, transT, transP,
        histT, histP);
    backtrace_kernel<<<128, 64, 0, stream>>>(scoreT, scoreP, histT, histP,
        endT, endP, out);
    finalize_kernel<<<1, 64, 0, stream>>>(numT, denT, numP, denP, out);
}